// Round 6
// baseline (431.085 us; speedup 1.0000x reference)
//
#include <hip/hip_runtime.h>
#include <hip/hip_bf16.h>
#include <string.h>

#define BB 4
#define LL 128
#define DM 256
#define VV 50257
#define VPAD 50304   // 786 tiles * 64; also 393 * 128
#define DW 768
#define HH 8
#define EE 32

typedef __attribute__((ext_vector_type(8))) short sh8;    // 8 bf16 = 4 VGPR
typedef __attribute__((ext_vector_type(4))) short sh4;    // 4 bf16 = 2 VGPR
typedef __attribute__((ext_vector_type(4))) float f32x4;  // MFMA accum

static __device__ inline unsigned short bfbits(float x) {
  __hip_bfloat16 h = __float2bfloat16(x);
  unsigned short u;
  __builtin_memcpy(&u, &h, 2);
  return u;
}

static __device__ inline sh8 ld8_b64(const short* p) {  // two 8B LDS reads
  sh4 lo = *(const sh4*)p;
  sh4 hi = *(const sh4*)(p + 4);
  return __builtin_shufflevector(lo, hi, 0, 1, 2, 3, 4, 5, 6, 7);
}

// ---------------- Q projection: Qb = bf16(scale * (tse @ Wq + bq)) ----------
__global__ __launch_bounds__(256) void qproj_kernel(
    const float* __restrict__ tse, const float* __restrict__ Wq,
    const float* __restrict__ bq, unsigned short* __restrict__ Qb) {
  __shared__ float row[DM];
  int r = blockIdx.x;     // 0..511
  int n = threadIdx.x;    // 0..255
  row[n] = tse[r * DM + n];
  __syncthreads();
  float acc = bq[n];
#pragma unroll 8
  for (int k = 0; k < DM; ++k)
    acc = fmaf(row[k], Wq[k * DM + n], acc);
  const float scale = 0.17677669529663687f;  // 1/sqrt(32), folded into Q
  Qb[r * DM + n] = bfbits(acc * scale);
}

// ------- transpose+cast Wk/Wv fp32 [768][256] -> bf16 [256][768] ------------
__global__ __launch_bounds__(256) void wtrans_kernel(
    const float* __restrict__ Wk, const float* __restrict__ Wv,
    unsigned short* __restrict__ Wkt, unsigned short* __restrict__ Wvt) {
  __shared__ float tileS[64][65];
  const float* src = blockIdx.z ? Wv : Wk;
  unsigned short* dst = blockIdx.z ? Wvt : Wkt;
  int k0 = blockIdx.x * 64, n0 = blockIdx.y * 64;
  int t = threadIdx.x;
  int c = t & 63, rb = t >> 6;
#pragma unroll
  for (int j = 0; j < 16; ++j) {
    int r = j * 4 + rb;
    tileS[r][c] = src[(size_t)(k0 + r) * DM + n0 + c];
  }
  __syncthreads();
#pragma unroll
  for (int j = 0; j < 16; ++j) {
    int r = j * 4 + rb;
    dst[(size_t)(n0 + r) * DW + k0 + c] = bfbits(tileS[c][r]);
  }
}

// ------------- K,V projection via MFMA: [VPAD,768]@[768,256] x2 -------------
// 2-deep software pipeline: loads for k-step s+2 are in flight across a full
// k-step; LDS double-buffered, ONE barrier per k-step.
#define KST2 36  // dword-stride 18: write rows 2-way (free), frag reads clean
struct LoadSet {
  float4 e0, e1, e2, e3;
  sh8 k0, k1, v0, v1;
};

static __device__ inline LoadSet issue_loads(
    const float* __restrict__ WE, const unsigned short* __restrict__ Wkt,
    const unsigned short* __restrict__ Wvt, int v0, int colbase, int sr,
    int skc, bool live, int kt) {
  LoadSet s;
  if (live) {
    const float* wep = WE + (size_t)(v0 + sr) * DW + kt * 32 + skc;
    s.e0 = *(const float4*)(wep + 0);
    s.e1 = *(const float4*)(wep + 4);
    s.e2 = *(const float4*)(wep + 8);
    s.e3 = *(const float4*)(wep + 12);
  } else {
    s.e0 = s.e1 = s.e2 = s.e3 = (float4){0.f, 0.f, 0.f, 0.f};
  }
  const unsigned short* kp = Wkt + (size_t)(colbase + sr) * DW + kt * 32 + skc;
  const unsigned short* vp = Wvt + (size_t)(colbase + sr) * DW + kt * 32 + skc;
  s.k0 = *(const sh8*)(kp + 0);
  s.k1 = *(const sh8*)(kp + 8);
  s.v0 = *(const sh8*)(vp + 0);
  s.v1 = *(const sh8*)(vp + 8);
  return s;
}

static __device__ inline void store_tile(short* __restrict__ WEb,
                                         short* __restrict__ Wkb,
                                         short* __restrict__ Wvb, int sr,
                                         int skc, const LoadSet& s) {
  sh4 w0 = {(short)bfbits(s.e0.x), (short)bfbits(s.e0.y),
            (short)bfbits(s.e0.z), (short)bfbits(s.e0.w)};
  sh4 w1 = {(short)bfbits(s.e1.x), (short)bfbits(s.e1.y),
            (short)bfbits(s.e1.z), (short)bfbits(s.e1.w)};
  sh4 w2 = {(short)bfbits(s.e2.x), (short)bfbits(s.e2.y),
            (short)bfbits(s.e2.z), (short)bfbits(s.e2.w)};
  sh4 w3 = {(short)bfbits(s.e3.x), (short)bfbits(s.e3.y),
            (short)bfbits(s.e3.z), (short)bfbits(s.e3.w)};
  short* eb = &WEb[sr * KST2 + skc];
  *(sh4*)(eb + 0) = w0;
  *(sh4*)(eb + 4) = w1;
  *(sh4*)(eb + 8) = w2;
  *(sh4*)(eb + 12) = w3;
  short* kb = &Wkb[sr * KST2 + skc];
  *(sh4*)(kb + 0) = __builtin_shufflevector(s.k0, s.k0, 0, 1, 2, 3);
  *(sh4*)(kb + 4) = __builtin_shufflevector(s.k0, s.k0, 4, 5, 6, 7);
  *(sh4*)(kb + 8) = __builtin_shufflevector(s.k1, s.k1, 0, 1, 2, 3);
  *(sh4*)(kb + 12) = __builtin_shufflevector(s.k1, s.k1, 4, 5, 6, 7);
  short* vb = &Wvb[sr * KST2 + skc];
  *(sh4*)(vb + 0) = __builtin_shufflevector(s.v0, s.v0, 0, 1, 2, 3);
  *(sh4*)(vb + 4) = __builtin_shufflevector(s.v0, s.v0, 4, 5, 6, 7);
  *(sh4*)(vb + 8) = __builtin_shufflevector(s.v1, s.v1, 0, 1, 2, 3);
  *(sh4*)(vb + 12) = __builtin_shufflevector(s.v1, s.v1, 4, 5, 6, 7);
}

static __device__ inline void mfma_step(const short* __restrict__ WEb,
                                        const short* __restrict__ Wkb,
                                        const short* __restrict__ Wvb, int wm,
                                        int wn, int a, int quad,
                                        f32x4 Ck[4][4], f32x4 Cv[4][4]) {
  sh8 A[4], Bk[4], Bv[4];
#pragma unroll
  for (int mb = 0; mb < 4; ++mb)
    A[mb] = ld8_b64(&WEb[(wm * 64 + mb * 16 + a) * KST2 + quad * 8]);
#pragma unroll
  for (int nb = 0; nb < 4; ++nb) {
    Bk[nb] = ld8_b64(&Wkb[((wn * 4 + nb) * 16 + a) * KST2 + quad * 8]);
    Bv[nb] = ld8_b64(&Wvb[((wn * 4 + nb) * 16 + a) * KST2 + quad * 8]);
  }
#pragma unroll
  for (int mb = 0; mb < 4; ++mb)
#pragma unroll
    for (int nb = 0; nb < 4; ++nb) {
      Ck[mb][nb] = __builtin_amdgcn_mfma_f32_16x16x32_bf16(A[mb], Bk[nb],
                                                           Ck[mb][nb], 0, 0, 0);
      Cv[mb][nb] = __builtin_amdgcn_mfma_f32_16x16x32_bf16(A[mb], Bv[nb],
                                                           Cv[mb][nb], 0, 0, 0);
    }
}

__global__ __launch_bounds__(256, 2) void kvproj_kernel(
    const float* __restrict__ WE, const unsigned short* __restrict__ Wkt,
    const unsigned short* __restrict__ Wvt, const float* __restrict__ bk,
    const float* __restrict__ bv, unsigned short* __restrict__ Kb,
    unsigned short* __restrict__ Vb) {
  __shared__ short WEb[2][128 * KST2];  // 2 x 9216 B
  __shared__ short Wkb[2][128 * KST2];
  __shared__ short Wvb[2][128 * KST2];  // 54 KB total -> 2 blocks/CU

  int bx = blockIdx.x;
  int v0 = (bx >> 1) * 128;
  int colbase = (bx & 1) * 128;
  int t = threadIdx.x;
  int w = t >> 6, lane = t & 63, a = lane & 15, quad = lane >> 4;
  int wm = w >> 1, wn = w & 1;
  int sr = t >> 1;
  int skc = (t & 1) * 16;
  const bool live = (v0 + sr) < VV;

  f32x4 Ck[4][4], Cv[4][4];
#pragma unroll
  for (int mb = 0; mb < 4; ++mb)
#pragma unroll
    for (int nb = 0; nb < 4; ++nb) {
      Ck[mb][nb] = (f32x4){0.f, 0.f, 0.f, 0.f};
      Cv[mb][nb] = (f32x4){0.f, 0.f, 0.f, 0.f};
    }

  LoadSet sA = issue_loads(WE, Wkt, Wvt, v0, colbase, sr, skc, live, 0);
  LoadSet sB = issue_loads(WE, Wkt, Wvt, v0, colbase, sr, skc, live, 1);
  store_tile(WEb[0], Wkb[0], Wvb[0], sr, skc, sA);

  for (int kt = 0; kt < 24; kt += 2) {
    __syncthreads();  // LDS buf0 (tile kt) ready
    mfma_step(WEb[0], Wkb[0], Wvb[0], wm, wn, a, quad, Ck, Cv);
    if (kt + 2 < 24)
      sA = issue_loads(WE, Wkt, Wvt, v0, colbase, sr, skc, live, kt + 2);
    store_tile(WEb[1], Wkb[1], Wvb[1], sr, skc, sB);  // tile kt+1
    __syncthreads();  // LDS buf1 ready
    mfma_step(WEb[1], Wkb[1], Wvb[1], wm, wn, a, quad, Ck, Cv);
    if (kt + 3 < 24)
      sB = issue_loads(WE, Wkt, Wvt, v0, colbase, sr, skc, live, kt + 3);
    if (kt + 2 < 24)
      store_tile(WEb[0], Wkb[0], Wvb[0], sr, skc, sA);  // tile kt+2
  }

  // epilogue: bias + store bf16; pad rows -> 0
  float bkv[4], bvv[4];
#pragma unroll
  for (int nb = 0; nb < 4; ++nb) {
    int n = colbase + (wn * 4 + nb) * 16 + a;
    bkv[nb] = bk[n];
    bvv[nb] = bv[n];
  }
#pragma unroll
  for (int mb = 0; mb < 4; ++mb)
#pragma unroll
    for (int nb = 0; nb < 4; ++nb)
#pragma unroll
      for (int r = 0; r < 4; ++r) {
        int m = v0 + wm * 64 + mb * 16 + quad * 4 + r;
        int n = colbase + (wn * 4 + nb) * 16 + a;
        bool ok = m < VV;
        Kb[(size_t)m * DM + n] = ok ? bfbits(Ck[mb][nb][r] + bkv[nb]) : 0;
        Vb[(size_t)m * DM + n] = ok ? bfbits(Cv[mb][nb][r] + bvv[nb]) : 0;
      }
}

// ---------------- zero the reprog accumulator -------------------------------
__global__ void zero_kernel(float* __restrict__ p, int n) {
  int i = blockIdx.x * blockDim.x + threadIdx.x;
  if (i < n) p[i] = 0.f;
}

// ---------------- MFMA attention over the vocab axis ------------------------
// Prefetch for tile+1 issued right after the score MFMAs consume af:
// in flight across softmax + 2 barriers + staging + phase 2.
#define PST 72  // row stride (bf16) for Pb/Vt: 144 B = 16 B aligned
__global__ __launch_bounds__(256) void attn_kernel(
    const unsigned short* __restrict__ Qb, const unsigned short* __restrict__ Kb,
    const unsigned short* __restrict__ Vb, float* __restrict__ reprog, int bpb) {
  __shared__ short Pb[LL * PST];  // 18432 B
  __shared__ short Vt[EE * PST];  //  4608 B

  int bh = blockIdx.x / bpb;
  int chunk = blockIdx.x - bh * bpb;
  int b = bh >> 3, h = bh & 7;
  int t = threadIdx.x;
  int w = t >> 6;         // wave 0..3
  int lane = t & 63;
  int a = lane & 15;      // MFMA n / m lane coord
  int quad = lane >> 4;   // 0..3
  int vr = t >> 2, e0 = (t & 3) * 8;  // V staging identity

  // hoist Q B-frags: frag[tau] holds Q rows l=tau*16+a, e=quad*8+j (16B each)
  sh8 qf[8];
  const unsigned short* qbase = Qb + (size_t)(b * LL) * DM + h * EE;
#pragma unroll
  for (int tau = 0; tau < 8; ++tau)
    qf[tau] = *(const sh8*)(qbase + (size_t)(tau * 16 + a) * DM + quad * 8);

  f32x4 C[2][2];  // accum: l = 32w + mb*16 + quad*4 + r, e = nb*16 + a
#pragma unroll
  for (int mb = 0; mb < 2; ++mb)
#pragma unroll
    for (int nb = 0; nb < 2; ++nb)
      C[mb][nb] = (f32x4){0.f, 0.f, 0.f, 0.f};

  const int ntiles = VPAD >> 6;  // 786

  // prefetch first tile
  sh8 af, vv;
  {
    int v0 = chunk << 6;
    af = *(const sh8*)(Kb + (size_t)(v0 + 16 * w + a) * DM + h * EE + quad * 8);
    vv = *(const sh8*)(Vb + (size_t)(v0 + vr) * DM + h * EE + e0);
  }

  for (int tile = chunk; tile < ntiles; tile += bpb) {
    // scores: 8 MFMAs on prefetched af
    f32x4 S[8];
#pragma unroll
    for (int tau = 0; tau < 8; ++tau) {
      f32x4 z = {0.f, 0.f, 0.f, 0.f};
      S[tau] = __builtin_amdgcn_mfma_f32_16x16x32_bf16(af, qf[tau], z, 0, 0, 0);
    }

    // issue next tile's loads NOW (af consumed; vv_n goes to fresh regs)
    sh8 af_n, vv_n;
    {
      int nt = tile + bpb;
      if (nt < ntiles) {
        int v0n = nt << 6;
        af_n = *(const sh8*)(Kb + (size_t)(v0n + 16 * w + a) * DM + h * EE +
                             quad * 8);
        vv_n = *(const sh8*)(Vb + (size_t)(v0n + vr) * DM + h * EE + e0);
      }
    }

    // register softmax over l per v-row r (shfl within 16-lane quad groups)
    float mx[4], sm[4], inv[4];
#pragma unroll
    for (int r = 0; r < 4; ++r) {
      float m = S[0][r];
#pragma unroll
      for (int tau = 1; tau < 8; ++tau) m = fmaxf(m, S[tau][r]);
      mx[r] = m;
    }
#pragma unroll
    for (int msk = 1; msk <= 8; msk <<= 1)
#pragma unroll
      for (int r = 0; r < 4; ++r)
        mx[r] = fmaxf(mx[r], __shfl_xor(mx[r], msk));
#pragma unroll
    for (int r = 0; r < 4; ++r) sm[r] = 0.f;
#pragma unroll
    for (int tau = 0; tau < 8; ++tau)
#pragma unroll
      for (int r = 0; r < 4; ++r) {
        float ex = __expf(S[tau][r] - mx[r]);
        S[tau][r] = ex;
        sm[r] += ex;
      }
#pragma unroll
    for (int msk = 1; msk <= 8; msk <<= 1)
#pragma unroll
      for (int r = 0; r < 4; ++r)
        sm[r] += __shfl_xor(sm[r], msk);
#pragma unroll
    for (int r = 0; r < 4; ++r) inv[r] = 1.f / sm[r];

    __syncthreads();  // prev phase2 frag reads done

    // stage V^T: Vt[e][v_local]
    {
      const short* vs = (const short*)&vv;
#pragma unroll
      for (int j = 0; j < 8; ++j)
        Vt[(e0 + j) * PST + vr] = vs[j];
    }
    // write P^T bf16: Pb[l = tau*16+a][v_local = 16w + quad*4 + r]
#pragma unroll
    for (int tau = 0; tau < 8; ++tau) {
      ushort4 pk;
      pk.x = bfbits(S[tau][0] * inv[0]);
      pk.y = bfbits(S[tau][1] * inv[1]);
      pk.z = bfbits(S[tau][2] * inv[2]);
      pk.w = bfbits(S[tau][3] * inv[3]);
      *(ushort4*)&Pb[(tau * 16 + a) * PST + 16 * w + quad * 4] = pk;
    }
    __syncthreads();

    // phase 2: C[l][e] += P^T[l][v] · V[v][e]
    sh8 Afr[2][2], Bfr[2][2];
#pragma unroll
    for (int mb = 0; mb < 2; ++mb)
#pragma unroll
      for (int kb = 0; kb < 2; ++kb)
        Afr[mb][kb] =
            *(const sh8*)&Pb[(32 * w + mb * 16 + a) * PST + kb * 32 + quad * 8];
#pragma unroll
    for (int kb = 0; kb < 2; ++kb)
#pragma unroll
      for (int nb = 0; nb < 2; ++nb)
        Bfr[kb][nb] = *(const sh8*)&Vt[(nb * 16 + a) * PST + kb * 32 + quad * 8];
#pragma unroll
    for (int kb = 0; kb < 2; ++kb)
#pragma unroll
      for (int mb = 0; mb < 2; ++mb)
#pragma unroll
        for (int nb = 0; nb < 2; ++nb)
          C[mb][nb] = __builtin_amdgcn_mfma_f32_16x16x32_bf16(
              Afr[mb][kb], Bfr[kb][nb], C[mb][nb], 0, 0, 0);

    af = af_n;
    vv = vv_n;
  }

  // epilogue: one atomicAdd burst per block
#pragma unroll
  for (int mb = 0; mb < 2; ++mb)
#pragma unroll
    for (int nb = 0; nb < 2; ++nb)
#pragma unroll
      for (int r = 0; r < 4; ++r) {
        int l = 32 * w + mb * 16 + quad * 4 + r;
        int e = nb * 16 + a;
        atomicAdd(&reprog[(size_t)(b * LL + l) * DM + h * EE + e], C[mb][nb][r]);
      }
}

// ---------------- output projection: reprog @ Wo + bo -> fp32 out -----------
__global__ __launch_bounds__(256) void outproj_kernel(
    const float* __restrict__ reprog, const float* __restrict__ Wo,
    const float* __restrict__ bo, float* __restrict__ out) {
  __shared__ float row[DM];
  int r = blockIdx.x, n = threadIdx.x;
  row[n] = reprog[r * DM + n];
  __syncthreads();
  float acc = bo[n];
#pragma unroll 8
  for (int k = 0; k < DM; ++k)
    acc = fmaf(row[k], Wo[k * DM + n], acc);
  out[r * DM + n] = acc;
}

extern "C" void kernel_launch(void* const* d_in, const int* in_sizes, int n_in,
                              void* d_out, int out_size, void* d_ws, size_t ws_size,
                              hipStream_t stream) {
  const float* tse = (const float*)d_in[0];
  const float* WE  = (const float*)d_in[1];
  const float* Wq  = (const float*)d_in[2];
  const float* bq  = (const float*)d_in[3];
  const float* Wk  = (const float*)d_in[4];
  const float* bk  = (const float*)d_in[5];
  const float* Wv  = (const float*)d_in[6];
  const float* bv  = (const float*)d_in[7];
  const float* Wo  = (const float*)d_in[8];
  const float* bo  = (const float*)d_in[9];
  float* out = (float*)d_out;

  // ws: Qb | Kb | Vb | X, where X holds Wkt+Wvt during kvproj and is then
  // reused as reprog (lifetimes disjoint: wtrans->kvproj | zero->attn->outproj)
  char* ws = (char*)d_ws;
  const size_t QB_BYTES = (size_t)BB * LL * DM * 2;    // 262144
  const size_t KV_BYTES = (size_t)VPAD * DM * 2;       // 25755648
  const size_t WT_BYTES = (size_t)DM * DW * 2;         // 393216
  unsigned short* Qb  = (unsigned short*)ws;
  unsigned short* Kb  = (unsigned short*)(ws + QB_BYTES);
  unsigned short* Vb  = (unsigned short*)(ws + QB_BYTES + KV_BYTES);
  char* X = ws + QB_BYTES + 2 * KV_BYTES;
  unsigned short* Wkt = (unsigned short*)X;
  unsigned short* Wvt = (unsigned short*)(X + WT_BYTES);
  float* reprog = (float*)X;  // aliases Wkt/Wvt AFTER kvproj is done

  const int BPB = 32;  // v-chunks per (b,h): grid = 32*32 = 1024 blocks

  wtrans_kernel<<<dim3(DW / 64, DM / 64, 2), 256, 0, stream>>>(Wk, Wv, Wkt, Wvt);
  qproj_kernel<<<BB * LL, 256, 0, stream>>>(tse, Wq, bq, Qb);
  kvproj_kernel<<<(VPAD / 128) * 2, 256, 0, stream>>>(WE, Wkt, Wvt, bk, bv, Kb, Vb);
  zero_kernel<<<(BB * LL * DM + 255) / 256, 256, 0, stream>>>(reprog, BB * LL * DM);
  attn_kernel<<<32 * BPB, 256, 0, stream>>>(Qb, Kb, Vb, reprog, BPB);
  outproj_kernel<<<BB * LL, 256, 0, stream>>>(reprog, Wo, bo, out);
}